// Round 1
// baseline (55.200 us; speedup 1.0000x reference)
//
#include <hip/hip_runtime.h>

// Problem constants
#define NL 64
#define NR 4096
#define NE 32
#define NF 64
#define NP 8

// RBF math:  z = (d - mu_e)/sigma,  rbf = exp(-z^2) = exp2(-((d - mu_e)*|1/sigma|)^2 * log2(e))
// |1/sigma| = 32/10 = 3.2 ; fold sqrt(log2 e) into the distance scale.
#define DSCALE 3.8435917081166390f   // 3.2 * sqrt(log2(e))
#define MUSTEP 1.2398683f            // (10/31) * DSCALE
#define EPS3   3e-10f                // eps added per coordinate (3 coords)

typedef _Float16 half8_t __attribute__((ext_vector_type(8)));
union H8 {
    half8_t h;
    uint4 u;
    _Float16 e[8];
};

#define DOT4(acc, a, b) \
    acc = fmaf((a).x, (b).x, fmaf((a).y, (b).y, fmaf((a).z, (b).z, fmaf((a).w, (b).w, acc))))

__global__ __launch_bounds__(256)
void ff_main(const float* __restrict__ lig_feat,    // [64][32][64]
             const float* __restrict__ rec_feat,    // [4096][32][64]
             const float* __restrict__ lig_coords,  // [8][64][3]
             const float* __restrict__ rec_coord,   // [4096][3]
             float* __restrict__ ws)                // [8] accumulators
{
    // lig row pitch 68 floats: 272B (16B aligned), bank stride 4 -> conflict-free reads
    __shared__ float lig_s[64][68];   // 17408 B
    __shared__ float rec_s[16][68];   // 4352 B
    __shared__ uint4 d_lds[1024];     // 16384 B : d''[pair l*16+r][p] as fp16x8
    __shared__ float wred[4][8];

    const int t   = threadIdx.x;
    const int bid = blockIdx.x;
    const int rb  = bid & 255;        // 256 r-blocks
    const int eb  = bid >> 8;         // 2 e-blocks
    const int r0  = rb * 16;
    const int e0  = eb * 16;
    const int tl  = t >> 4;           // 0..15  -> thread's l rows: tl + 16*i
    const int tr  = t & 15;           // 0..15  -> thread's r: r0 + tr

    // ---- prologue: distances (once per block), stored as fp16 d*DSCALE ----
    const float rx = rec_coord[(r0 + tr) * 3 + 0];
    const float ry = rec_coord[(r0 + tr) * 3 + 1];
    const float rz = rec_coord[(r0 + tr) * 3 + 2];
#pragma unroll
    for (int i = 0; i < 4; ++i) {
        const int l = tl + 16 * i;
        H8 pack;
#pragma unroll
        for (int p = 0; p < NP; ++p) {
            const float lx = lig_coords[(p * NL + l) * 3 + 0];
            const float ly = lig_coords[(p * NL + l) * 3 + 1];
            const float lz = lig_coords[(p * NL + l) * 3 + 2];
            const float dx = lx - rx, dy = ly - ry, dz = lz - rz;
            const float d2 = fmaf(dx, dx, fmaf(dy, dy, fmaf(dz, dz, EPS3)));
            pack.e[p] = (_Float16)(sqrtf(d2) * DSCALE);
        }
        d_lds[l * 16 + tr] = pack.u;   // read back only by this same thread
    }

    float U[NP];
#pragma unroll
    for (int p = 0; p < NP; ++p) U[p] = 0.f;

    for (int ee = 0; ee < 16; ++ee) {
        const int e = e0 + ee;
        __syncthreads();  // protect LDS tiles from previous iteration's readers
        // stage lig[:, e, :] : 64 rows x 64 floats
#pragma unroll
        for (int j = 0; j < 4; ++j) {
            const int k = t + j * 256;
            const int row = k >> 4, c = k & 15;
            *(float4*)&lig_s[row][c * 4] =
                *(const float4*)&lig_feat[(row * NE + e) * NF + c * 4];
        }
        // stage rec[r0..r0+15, e, :] : 16 rows x 64 floats (one float4/thread)
        {
            const int row = t >> 4, c = t & 15;
            *(float4*)&rec_s[row][c * 4] =
                *(const float4*)&rec_feat[((r0 + row) * NE + e) * NF + c * 4];
        }
        __syncthreads();

        // 4 dot products (l = tl+16i, r = tr) of length 64
        float dot[4] = {0.f, 0.f, 0.f, 0.f};
#pragma unroll
        for (int fc = 0; fc < 16; ++fc) {
            const float4 b  = *(const float4*)&rec_s[tr][fc * 4];
            const float4 a0 = *(const float4*)&lig_s[tl +  0][fc * 4];
            const float4 a1 = *(const float4*)&lig_s[tl + 16][fc * 4];
            const float4 a2 = *(const float4*)&lig_s[tl + 32][fc * 4];
            const float4 a3 = *(const float4*)&lig_s[tl + 48][fc * 4];
            DOT4(dot[0], a0, b);
            DOT4(dot[1], a1, b);
            DOT4(dot[2], a2, b);
            DOT4(dot[3], a3, b);
        }

        const float mu2 = (float)e * MUSTEP;
#pragma unroll
        for (int i = 0; i < 4; ++i) {
            H8 pk;
            pk.u = d_lds[(tl + 16 * i) * 16 + tr];
            const float a = dot[i];
#pragma unroll
            for (int p = 0; p < NP; ++p) {
                const float z = (float)pk.e[p] - mu2;
                U[p] = fmaf(a, __builtin_amdgcn_exp2f(-(z * z)), U[p]);
            }
        }
    }

    // ---- block reduction ----
    const int lane = t & 63, wv = t >> 6;
#pragma unroll
    for (int p = 0; p < NP; ++p) {
        float v = U[p];
        for (int off = 32; off; off >>= 1) v += __shfl_down(v, off, 64);
        if (lane == 0) wred[wv][p] = v;
    }
    __syncthreads();
    if (t < NP) {
        const float s = wred[0][t] + wred[1][t] + wred[2][t] + wred[3][t];
        atomicAdd(&ws[t], s);
    }
}

__global__ void ff_zero(float* __restrict__ ws) {
    if (threadIdx.x < NP) ws[threadIdx.x] = 0.f;
}

__global__ void ff_fin(const float* __restrict__ ws,
                       const float* __restrict__ w,
                       const float* __restrict__ b,
                       float* __restrict__ out) {
    if (threadIdx.x < NP) out[threadIdx.x] = fmaf(ws[threadIdx.x], w[0], b[0]);
}

extern "C" void kernel_launch(void* const* d_in, const int* in_sizes, int n_in,
                              void* d_out, int out_size, void* d_ws, size_t ws_size,
                              hipStream_t stream) {
    const float* lig_feat   = (const float*)d_in[0];
    const float* rec_feat   = (const float*)d_in[1];
    const float* lig_coords = (const float*)d_in[2];
    const float* rec_coord  = (const float*)d_in[3];
    const float* weight     = (const float*)d_in[4];
    const float* bias       = (const float*)d_in[5];
    float* out = (float*)d_out;
    float* ws  = (float*)d_ws;

    hipLaunchKernelGGL(ff_zero, dim3(1), dim3(64), 0, stream, ws);
    hipLaunchKernelGGL(ff_main, dim3(512), dim3(256), 0, stream,
                       lig_feat, rec_feat, lig_coords, rec_coord, ws);
    hipLaunchKernelGGL(ff_fin, dim3(1), dim3(64), 0, stream, ws, weight, bias, out);
}

// Round 2
// 54.307 us; speedup vs baseline: 1.0164x; 1.0164x over previous
//
#include <hip/hip_runtime.h>

// Problem constants
#define NL 64
#define NR 4096
#define NE 32
#define NF 64
#define NP 8

// RBF math:  z = (d - mu_e)/sigma,  rbf = exp(-z^2) = exp2(-((d - mu_e)*3.2)^2 * log2(e))
// Fold sqrt(log2 e) into the distance scale so rbf = exp2(-(ds - e*MUSTEP)^2).
#define DSCALE 3.8435917081166390f   // 3.2 * sqrt(log2(e))
#define MUSTEP 1.2398683f            // (10/31) * DSCALE
#define EPS3   3e-10f                // eps added per coordinate (3 coords)

typedef _Float16 half8_t __attribute__((ext_vector_type(8)));
union H8 {
    half8_t h;
    uint4 u;
    _Float16 e[8];
};

#define DOT4(acc, a, b) \
    acc = fmaf((a).x, (b).x, fmaf((a).y, (b).y, fmaf((a).z, (b).z, fmaf((a).w, (b).w, acc))))

// Grid: 64 r-blocks x 8 e-blocks = 512. Block: 256 threads as 16(tl) x 16(tr).
// Each thread owns a 4x4 (l,r) tile: l = tl+16i, r = r0+tr+16j  -> 2 B LDS/FMA.
__global__ __launch_bounds__(256, 2)
void ff_main(const float* __restrict__ lig_feat,    // [64][32][64]
             const float* __restrict__ rec_feat,    // [4096][32][64]
             const float* __restrict__ lig_coords,  // [8][64][3]
             const float* __restrict__ rec_coord,   // [4096][3]
             float* __restrict__ ws)                // [8] accumulators
{
    // pitch 68 floats: row-to-row bank shift of 4 -> worst 2-way conflict (free)
    __shared__ float lig_s[64][68];   // 17408 B
    __shared__ float rec_s[64][68];   // 17408 B
    __shared__ float wred[4][8];

    const int t   = threadIdx.x;
    const int bid = blockIdx.x;
    const int rb  = bid & 63;         // 64 r-blocks
    const int eb  = bid >> 6;         // 8 e-blocks
    const int r0  = rb * 64;
    const int e0  = eb * 4;
    const int tl  = t >> 4;           // 0..15 -> l rows: tl + 16*i
    const int tr  = t & 15;           // 0..15 -> r rows: r0 + tr + 16*j

    // ---- prologue: 4x4x8 distances into packed-fp16 registers ----
    float rx[4], ry[4], rz[4];
#pragma unroll
    for (int j = 0; j < 4; ++j) {
        const int r = r0 + tr + 16 * j;
        rx[j] = rec_coord[r * 3 + 0];
        ry[j] = rec_coord[r * 3 + 1];
        rz[j] = rec_coord[r * 3 + 2];
    }
    H8 d_reg[4][4];
#pragma unroll
    for (int i = 0; i < 4; ++i) {
        const int l = tl + 16 * i;
#pragma unroll
        for (int p = 0; p < NP; ++p) {
            const float lx = lig_coords[(p * NL + l) * 3 + 0];
            const float ly = lig_coords[(p * NL + l) * 3 + 1];
            const float lz = lig_coords[(p * NL + l) * 3 + 2];
#pragma unroll
            for (int j = 0; j < 4; ++j) {
                const float dx = lx - rx[j], dy = ly - ry[j], dz = lz - rz[j];
                const float d2 = fmaf(dx, dx, fmaf(dy, dy, fmaf(dz, dz, EPS3)));
                d_reg[i][j].e[p] = (_Float16)(__builtin_amdgcn_sqrtf(d2) * DSCALE);
            }
        }
    }

    float U[NP];
#pragma unroll
    for (int p = 0; p < NP; ++p) U[p] = 0.f;

    for (int ee = 0; ee < 4; ++ee) {
        const int e = e0 + ee;
        __syncthreads();  // protect LDS tiles from previous iteration's readers
        // stage lig[:, e, :] and rec[r0..r0+63, e, :] : each 64 rows x 64 floats
#pragma unroll
        for (int j = 0; j < 4; ++j) {
            const int k = t + j * 256;
            const int row = k >> 4, c = k & 15;
            *(float4*)&lig_s[row][c * 4] =
                *(const float4*)&lig_feat[(row * NE + e) * NF + c * 4];
            *(float4*)&rec_s[row][c * 4] =
                *(const float4*)&rec_feat[((r0 + row) * NE + e) * NF + c * 4];
        }
        __syncthreads();

        // 16 dot products (4l x 4r) of length 64: 8 ds_read_b128 -> 64 FMA per fc
        float acc[4][4];
#pragma unroll
        for (int i = 0; i < 4; ++i)
#pragma unroll
            for (int j = 0; j < 4; ++j) acc[i][j] = 0.f;

#pragma unroll
        for (int fc = 0; fc < 16; ++fc) {
            float4 a[4], b[4];
#pragma unroll
            for (int i = 0; i < 4; ++i) a[i] = *(const float4*)&lig_s[tl + 16 * i][fc * 4];
#pragma unroll
            for (int j = 0; j < 4; ++j) b[j] = *(const float4*)&rec_s[tr + 16 * j][fc * 4];
#pragma unroll
            for (int i = 0; i < 4; ++i)
#pragma unroll
                for (int j = 0; j < 4; ++j) DOT4(acc[i][j], a[i], b[j]);
        }

        // RBF accumulate: U[p] += acc * exp2(-(ds - mu_e)^2)
        const float mu2 = (float)e * MUSTEP;
#pragma unroll
        for (int i = 0; i < 4; ++i) {
#pragma unroll
            for (int j = 0; j < 4; ++j) {
                const float a = acc[i][j];
                const H8 pk = d_reg[i][j];
#pragma unroll
                for (int p = 0; p < NP; ++p) {
                    const float z = (float)pk.e[p] - mu2;
                    U[p] = fmaf(a, __builtin_amdgcn_exp2f(-(z * z)), U[p]);
                }
            }
        }
    }

    // ---- block reduction ----
    const int lane = t & 63, wv = t >> 6;
#pragma unroll
    for (int p = 0; p < NP; ++p) {
        float v = U[p];
        for (int off = 32; off; off >>= 1) v += __shfl_down(v, off, 64);
        if (lane == 0) wred[wv][p] = v;
    }
    __syncthreads();
    if (t < NP) {
        const float s = wred[0][t] + wred[1][t] + wred[2][t] + wred[3][t];
        atomicAdd(&ws[t], s);
    }
}

__global__ void ff_zero(float* __restrict__ ws) {
    if (threadIdx.x < NP) ws[threadIdx.x] = 0.f;
}

__global__ void ff_fin(const float* __restrict__ ws,
                       const float* __restrict__ w,
                       const float* __restrict__ b,
                       float* __restrict__ out) {
    if (threadIdx.x < NP) out[threadIdx.x] = fmaf(ws[threadIdx.x], w[0], b[0]);
}

extern "C" void kernel_launch(void* const* d_in, const int* in_sizes, int n_in,
                              void* d_out, int out_size, void* d_ws, size_t ws_size,
                              hipStream_t stream) {
    const float* lig_feat   = (const float*)d_in[0];
    const float* rec_feat   = (const float*)d_in[1];
    const float* lig_coords = (const float*)d_in[2];
    const float* rec_coord  = (const float*)d_in[3];
    const float* weight     = (const float*)d_in[4];
    const float* bias       = (const float*)d_in[5];
    float* out = (float*)d_out;
    float* ws  = (float*)d_ws;

    hipLaunchKernelGGL(ff_zero, dim3(1), dim3(64), 0, stream, ws);
    hipLaunchKernelGGL(ff_main, dim3(512), dim3(256), 0, stream,
                       lig_feat, rec_feat, lig_coords, rec_coord, ws);
    hipLaunchKernelGGL(ff_fin, dim3(1), dim3(64), 0, stream, ws, weight, bias, out);
}

// Round 3
// 35.634 us; speedup vs baseline: 1.5491x; 1.5240x over previous
//
#include <hip/hip_runtime.h>

// Problem constants
#define NL 64
#define NR 4096
#define NE 32
#define NF 64
#define NP 8

// RBF math:  rbf = exp(-((d - mu_e)*3.2)^2) = exp2(-(d*DSCALE - e*MUSTEP)^2)
#define DSCALE 3.8435917081166390f   // 3.2 * sqrt(log2(e))
#define MUSTEP 1.2398683f            // (10/31) * DSCALE
#define EPS3   3e-10f                // eps added per coordinate (3 coords)
#define PITCH  72                    // fp16 elems per LDS row (64 + 8 pad = 144 B)

typedef _Float16 f16x8 __attribute__((ext_vector_type(8)));
typedef float    f32x4 __attribute__((ext_vector_type(4)));

// Grid: 256 r-blocks x 4 e-blocks. Block: 256 thr = 4 waves; wave wv owns the
// 16x16 MFMA tile (l = wv*16 .. +16, r = r0 .. r0+16) and loops 8 e's.
// atn tile via mfma_f32_16x16x32_f16 (K=F=64 as 2 chained MFMAs), fp16 staged.
__global__ __launch_bounds__(256, 4)
void ff_main(const float* __restrict__ lig_feat,    // [64][32][64]
             const float* __restrict__ rec_feat,    // [4096][32][64]
             const float* __restrict__ lig_coords,  // [8][64][3]
             const float* __restrict__ rec_coord,   // [4096][3]
             float* __restrict__ ws)                // [8] accumulators
{
    __shared__ __align__(16) _Float16 lig_s[2][64 * PITCH];  // 2 x 9216 B
    __shared__ __align__(16) _Float16 rec_s[2][16 * PITCH];  // 2 x 2304 B
    __shared__ float wred[4][8];

    const int t    = threadIdx.x;
    const int bid  = blockIdx.x;
    const int rb   = bid & 255;       // 256 r-blocks
    const int eb   = bid >> 8;        // 4 e-blocks
    const int r0   = rb * 16;
    const int e0   = eb * 8;
    const int lane = t & 63;
    const int wv   = t >> 6;
    const int l0   = wv * 16;
    const int cn   = lane & 15;       // MFMA col (= r offset) & A/B frag row
    const int kg   = lane >> 4;       // k-group 0..3

    // ---- distances for this lane's C elements: l = l0 + kg*4 + reg, r = r0+cn
    const int rr = r0 + cn;
    const float rx = rec_coord[rr * 3 + 0];
    const float ry = rec_coord[rr * 3 + 1];
    const float rz = rec_coord[rr * 3 + 2];
    float ds[4][NP];
#pragma unroll
    for (int reg = 0; reg < 4; ++reg) {
        const int l = l0 + kg * 4 + reg;
#pragma unroll
        for (int p = 0; p < NP; ++p) {
            const float lx = lig_coords[(p * NL + l) * 3 + 0];
            const float ly = lig_coords[(p * NL + l) * 3 + 1];
            const float lz = lig_coords[(p * NL + l) * 3 + 2];
            const float dx = lx - rx, dy = ly - ry, dz = lz - rz;
            const float d2 = fmaf(dx, dx, fmaf(dy, dy, fmaf(dz, dz, EPS3)));
            ds[reg][p] = sqrtf(d2) * DSCALE;
        }
    }

    // ---- staging geometry ----
    const int sl   = t >> 2;          // lig row 0..63
    const int sf   = (t & 3) * 16;    // lig f base
    const int srow = t >> 4;          // rec row 0..15
    const int srf  = (t & 15) * 4;    // rec f base

    float4 Lr[4];
    float4 Rr;
    auto stage_load = [&](int e) {
        const float* lp = &lig_feat[(sl * NE + e) * NF + sf];
        Lr[0] = *(const float4*)(lp + 0);
        Lr[1] = *(const float4*)(lp + 4);
        Lr[2] = *(const float4*)(lp + 8);
        Lr[3] = *(const float4*)(lp + 12);
        Rr = *(const float4*)&rec_feat[((r0 + srow) * NE + e) * NF + srf];
    };
    auto stage_write = [&](int buf) {
#pragma unroll
        for (int i = 0; i < 4; ++i) {
            union { _Float16 h[4]; uint2 u; } pk;
            pk.h[0] = (_Float16)Lr[i].x; pk.h[1] = (_Float16)Lr[i].y;
            pk.h[2] = (_Float16)Lr[i].z; pk.h[3] = (_Float16)Lr[i].w;
            *(uint2*)&lig_s[buf][sl * PITCH + sf + 4 * i] = pk.u;
        }
        union { _Float16 h[4]; uint2 u; } pr;
        pr.h[0] = (_Float16)Rr.x; pr.h[1] = (_Float16)Rr.y;
        pr.h[2] = (_Float16)Rr.z; pr.h[3] = (_Float16)Rr.w;
        *(uint2*)&rec_s[buf][srow * PITCH + srf] = pr.u;
    };

    float U[NP];
#pragma unroll
    for (int p = 0; p < NP; ++p) U[p] = 0.f;

    stage_load(e0);
    stage_write(0);
    int cur = 0;
    for (int ee = 0; ee < 8; ++ee) {
        __syncthreads();                       // buf[cur] ready for all
        if (ee < 7) stage_load(e0 + ee + 1);   // global loads fly over compute

        // fragments: A row = l0+cn, B row = r tile row cn; k = kg*8 (+32)
        const _Float16* la = &lig_s[cur][(l0 + cn) * PITCH + kg * 8];
        const _Float16* lb = &rec_s[cur][cn * PITCH + kg * 8];
        const f16x8 a0 = *(const f16x8*)(la);
        const f16x8 a1 = *(const f16x8*)(la + 32);
        const f16x8 b0 = *(const f16x8*)(lb);
        const f16x8 b1 = *(const f16x8*)(lb + 32);
        f32x4 C = {0.f, 0.f, 0.f, 0.f};
        C = __builtin_amdgcn_mfma_f32_16x16x32_f16(a0, b0, C, 0, 0, 0);
        C = __builtin_amdgcn_mfma_f32_16x16x32_f16(a1, b1, C, 0, 0, 0);

        const float mu = (float)(e0 + ee) * MUSTEP;
#pragma unroll
        for (int reg = 0; reg < 4; ++reg) {
            const float a = C[reg];
#pragma unroll
            for (int p = 0; p < NP; ++p) {
                const float z = ds[reg][p] - mu;
                U[p] = fmaf(a, __builtin_amdgcn_exp2f(-(z * z)), U[p]);
            }
        }

        if (ee < 7) stage_write(cur ^ 1);      // other threads read buf[cur] only
        cur ^= 1;
    }

    // ---- block reduction ----
#pragma unroll
    for (int p = 0; p < NP; ++p) {
        float v = U[p];
        for (int off = 32; off; off >>= 1) v += __shfl_down(v, off, 64);
        if (lane == 0) wred[wv][p] = v;
    }
    __syncthreads();
    if (t < NP) {
        const float s = wred[0][t] + wred[1][t] + wred[2][t] + wred[3][t];
        atomicAdd(&ws[t], s);
    }
}

__global__ void ff_zero(float* __restrict__ ws) {
    if (threadIdx.x < NP) ws[threadIdx.x] = 0.f;
}

__global__ void ff_fin(const float* __restrict__ ws,
                       const float* __restrict__ w,
                       const float* __restrict__ b,
                       float* __restrict__ out) {
    if (threadIdx.x < NP) out[threadIdx.x] = fmaf(ws[threadIdx.x], w[0], b[0]);
}

extern "C" void kernel_launch(void* const* d_in, const int* in_sizes, int n_in,
                              void* d_out, int out_size, void* d_ws, size_t ws_size,
                              hipStream_t stream) {
    const float* lig_feat   = (const float*)d_in[0];
    const float* rec_feat   = (const float*)d_in[1];
    const float* lig_coords = (const float*)d_in[2];
    const float* rec_coord  = (const float*)d_in[3];
    const float* weight     = (const float*)d_in[4];
    const float* bias       = (const float*)d_in[5];
    float* out = (float*)d_out;
    float* ws  = (float*)d_ws;

    hipLaunchKernelGGL(ff_zero, dim3(1), dim3(64), 0, stream, ws);
    hipLaunchKernelGGL(ff_main, dim3(1024), dim3(256), 0, stream,
                       lig_feat, rec_feat, lig_coords, rec_coord, ws);
    hipLaunchKernelGGL(ff_fin, dim3(1), dim3(64), 0, stream, ws, weight, bias, out);
}

// Round 4
// 28.228 us; speedup vs baseline: 1.9555x; 1.2624x over previous
//
#include <hip/hip_runtime.h>

// Problem constants
#define NL 64
#define NR 4096
#define NE 32
#define NF 64
#define NP 8

// RBF math:  rbf = exp(-((d - mu_e)*3.2)^2) = exp2(-(d*DSCALE - e*MUSTEP)^2)
#define DSCALE 3.8435917081166390f   // 3.2 * sqrt(log2(e))
#define MUSTEP 1.2398683f            // (10/31) * DSCALE
#define EPS3   3e-10f                // eps added per coordinate (3 coords)

typedef _Float16 f16x8 __attribute__((ext_vector_type(8)));
typedef float    f32x4 __attribute__((ext_vector_type(4)));

// LDS map (bytes), fp16, 128 B per (e,row) with XOR-swizzled 16-B slots:
//   lig [4e][64l][64f]  @ 0      : 32768 B   (row pitch 128 B, e pitch 8192 B)
//   rec [4e][16r][64f]  @ 32768  :  8192 B   (row pitch 128 B, e pitch 2048 B)
// swizzle: byte_in_row = (2*f) ^ ((row & 7) << 4)  -- applied on BOTH sides.
#define LIG_B 0
#define REC_B 32768
#define NBLK  2048                   // 256 r-blocks x 8 e-blocks

// Block: 256 thr = 4 waves; wave wv owns MFMA tile l=wv*16..+16, r=r0..+16,
// loops 4 e's barrier-free out of single-shot-staged LDS.
__global__ __launch_bounds__(256, 4)
void ff_main(const float* __restrict__ lig_feat,    // [64][32][64]
             const float* __restrict__ rec_feat,    // [4096][32][64]
             const float* __restrict__ lig_coords,  // [8][64][3]
             const float* __restrict__ rec_coord,   // [4096][3]
             float* __restrict__ ws)                // [8][NBLK] partials
{
    __shared__ __align__(16) char smem[40960];

    const int t    = threadIdx.x;
    const int bid  = blockIdx.x;
    const int rb   = bid & 255;       // 256 r-blocks
    const int eb   = bid >> 8;        // 8 e-blocks
    const int r0   = rb * 16;
    const int e0   = eb * 4;
    const int lane = t & 63;
    const int wv   = t >> 6;
    const int l0   = wv * 16;
    const int cn   = lane & 15;       // MFMA col / frag row
    const int kg   = lane >> 4;       // k-group 0..3

    // ---- single-shot staging: rec (4 passes) + lig (16 passes), fp32->fp16 ----
#pragma unroll
    for (int j = 0; j < 4; ++j) {
        const int idx = j * 256 + t;
        const int e = idx >> 8, r = (idx >> 4) & 15, fq = idx & 15;
        const float4 v = *(const float4*)&rec_feat[((r0 + r) * NE + e0 + e) * NF + fq * 4];
        union { _Float16 h[4]; uint2 u; } pk;
        pk.h[0] = (_Float16)v.x; pk.h[1] = (_Float16)v.y;
        pk.h[2] = (_Float16)v.z; pk.h[3] = (_Float16)v.w;
        *(uint2*)(smem + REC_B + e * 2048 + r * 128 + ((8 * fq) ^ ((r & 7) << 4))) = pk.u;
    }
#pragma unroll 8
    for (int j = 0; j < 16; ++j) {
        const int idx = j * 256 + t;
        const int e = idx >> 10, rem = idx & 1023, l = rem >> 4, fq = rem & 15;
        const float4 v = *(const float4*)&lig_feat[(l * NE + e0 + e) * NF + fq * 4];
        union { _Float16 h[4]; uint2 u; } pk;
        pk.h[0] = (_Float16)v.x; pk.h[1] = (_Float16)v.y;
        pk.h[2] = (_Float16)v.z; pk.h[3] = (_Float16)v.w;
        *(uint2*)(smem + LIG_B + e * 8192 + l * 128 + ((8 * fq) ^ ((l & 7) << 4))) = pk.u;
    }

    // ---- distances for this lane's C elements: l = l0+kg*4+reg, r = r0+cn ----
    const int rr = r0 + cn;
    const float rx = rec_coord[rr * 3 + 0];
    const float ry = rec_coord[rr * 3 + 1];
    const float rz = rec_coord[rr * 3 + 2];
    float ds[4][NP];
#pragma unroll
    for (int reg = 0; reg < 4; ++reg) {
        const int l = l0 + kg * 4 + reg;
#pragma unroll
        for (int p = 0; p < NP; ++p) {
            const float lx = lig_coords[(p * NL + l) * 3 + 0];
            const float ly = lig_coords[(p * NL + l) * 3 + 1];
            const float lz = lig_coords[(p * NL + l) * 3 + 2];
            const float dx = lx - rx, dy = ly - ry, dz = lz - rz;
            const float d2 = fmaf(dx, dx, fmaf(dy, dy, fmaf(dz, dz, EPS3)));
            ds[reg][p] = __builtin_amdgcn_sqrtf(d2) * DSCALE;
        }
    }

    __syncthreads();   // the only staging barrier

    // frag byte offsets (swizzled, e-invariant parts)
    const int sx = (cn & 7) << 4;
    const int a_row = LIG_B + (l0 + cn) * 128;
    const int b_row = REC_B + cn * 128;
    const int a0o = a_row + ((kg * 16) ^ sx);
    const int a1o = a_row + ((kg * 16 + 64) ^ sx);
    const int b0o = b_row + ((kg * 16) ^ sx);
    const int b1o = b_row + ((kg * 16 + 64) ^ sx);

    float U[NP];
#pragma unroll
    for (int p = 0; p < NP; ++p) U[p] = 0.f;

#pragma unroll
    for (int ee = 0; ee < 4; ++ee) {
        const f16x8 a0 = *(const f16x8*)(smem + a0o + ee * 8192);
        const f16x8 a1 = *(const f16x8*)(smem + a1o + ee * 8192);
        const f16x8 b0 = *(const f16x8*)(smem + b0o + ee * 2048);
        const f16x8 b1 = *(const f16x8*)(smem + b1o + ee * 2048);
        f32x4 C = {0.f, 0.f, 0.f, 0.f};
        C = __builtin_amdgcn_mfma_f32_16x16x32_f16(a0, b0, C, 0, 0, 0);
        C = __builtin_amdgcn_mfma_f32_16x16x32_f16(a1, b1, C, 0, 0, 0);

        const float mu = (float)(e0 + ee) * MUSTEP;
#pragma unroll
        for (int reg = 0; reg < 4; ++reg) {
            const float a = C[reg];
#pragma unroll
            for (int p = 0; p < NP; ++p) {
                const float z = ds[reg][p] - mu;
                U[p] = fmaf(a, __builtin_amdgcn_exp2f(-(z * z)), U[p]);
            }
        }
    }

    // ---- reduce: wave shfl, then cross-wave via reused LDS, partials to ws ----
#pragma unroll
    for (int p = 0; p < NP; ++p) {
        float v = U[p];
        for (int off = 32; off; off >>= 1) v += __shfl_down(v, off, 64);
        U[p] = v;
    }
    __syncthreads();                  // all LDS frag reads done -> safe to reuse
    float* wred = (float*)smem;
    if (lane == 0) {
#pragma unroll
        for (int p = 0; p < NP; ++p) wred[wv * 8 + p] = U[p];
    }
    __syncthreads();
    if (t < NP)
        ws[t * NBLK + bid] = wred[t] + wred[8 + t] + wred[16 + t] + wred[24 + t];
}

__global__ __launch_bounds__(512)
void ff_fin(const float* __restrict__ ws,
            const float* __restrict__ w,
            const float* __restrict__ b,
            float* __restrict__ out) {
    const int t = threadIdx.x, lane = t & 63, p = t >> 6;
    float s = 0.f;
#pragma unroll
    for (int j = 0; j < NBLK / 64; ++j) s += ws[p * NBLK + j * 64 + lane];
    for (int off = 32; off; off >>= 1) s += __shfl_down(s, off, 64);
    if (lane == 0) out[p] = fmaf(s, w[0], b[0]);
}

extern "C" void kernel_launch(void* const* d_in, const int* in_sizes, int n_in,
                              void* d_out, int out_size, void* d_ws, size_t ws_size,
                              hipStream_t stream) {
    const float* lig_feat   = (const float*)d_in[0];
    const float* rec_feat   = (const float*)d_in[1];
    const float* lig_coords = (const float*)d_in[2];
    const float* rec_coord  = (const float*)d_in[3];
    const float* weight     = (const float*)d_in[4];
    const float* bias       = (const float*)d_in[5];
    float* out = (float*)d_out;
    float* ws  = (float*)d_ws;

    hipLaunchKernelGGL(ff_main, dim3(NBLK), dim3(256), 0, stream,
                       lig_feat, rec_feat, lig_coords, rec_coord, ws);
    hipLaunchKernelGGL(ff_fin, dim3(1), dim3(512), 0, stream,
                       ws, weight, bias, out);
}